// Round 17
// baseline (1230.471 us; speedup 1.0000x reference)
//
#include <hip/hip_runtime.h>
#include <hip/hip_bf16.h>

// Poolformer forward, bf16-MFMA GEMMs + MFMA flash attention.
// Dead code proofs (reference quirks we exploit):
//  1. m_glob = triu(ones((32,31)), k=-97) is all-True -> ALL global keys masked
//     -> softmax weight exactly 0 -> global transformer branch skipped.
//  2. v2 = k2 in local_attn: attention VALUES are the KEYS -> v-half of x@wkv dead.
// Scratch: d_ws holds only buffers live during the final logits GEMM; all other
// intermediates live in d_out (fully rewritten by the logits GEMM every call).

#define DIMM   768
#define SEQLEN 4096
#define NHEADS 12
#define DH     64
#define WWIN   128
#define NBUCK  32
#define NDEPTH 4
#define FFDIM  3072
#define NTOK   32000
#define QKLD   1536
#define NEG_MAX (-3.402823466e38f)

typedef unsigned short u16;
typedef __attribute__((ext_vector_type(8))) short bf16x8;
typedef __attribute__((ext_vector_type(4))) float f32x4;

#define GLOAD16(gp, lp) \
  __builtin_amdgcn_global_load_lds((const __attribute__((address_space(1))) void*)(gp), \
                                   (__attribute__((address_space(3))) void*)(lp), 16, 0, 0)

#define BAR()      __builtin_amdgcn_s_barrier()
#define SBAR()     __builtin_amdgcn_sched_barrier(0)
#define PRIO(x)    __builtin_amdgcn_s_setprio(x)
#define VMDRAIN()  asm volatile("s_waitcnt vmcnt(0)" ::: "memory")

// ---------------- embed ----------------
__global__ __launch_bounds__(256) void embed_kernel(
    const int* __restrict__ x, const float* __restrict__ tok,
    const float* __restrict__ pos, float* __restrict__ h) {
  int row = blockIdx.x;
  int t = threadIdx.x;
  int tk = x[row];
  const float* te = tok + (size_t)tk * DIMM;
  const float* pe = pos + (size_t)row * DIMM;
  float* hr = h + (size_t)row * DIMM;
  hr[t]       = te[t]       + pe[t];
  hr[t + 256] = te[t + 256] + pe[t + 256];
  hr[t + 512] = te[t + 512] + pe[t + 512];
}

// ---------------- layernorm: f32 in, bf16 out ----------------
__global__ __launch_bounds__(256) void ln_kernel(
    const float* __restrict__ in, const float* __restrict__ gam,
    const float* __restrict__ bet, __hip_bfloat16* __restrict__ out) {
  int row = blockIdx.x;
  int t = threadIdx.x;
  const float* xr = in + (size_t)row * DIMM;
  float v0 = xr[t], v1 = xr[t + 256], v2 = xr[t + 512];
  float s  = v0 + v1 + v2;
  float s2 = v0 * v0 + v1 * v1 + v2 * v2;
  #pragma unroll
  for (int o = 32; o > 0; o >>= 1) {
    s  += __shfl_down(s, o);
    s2 += __shfl_down(s2, o);
  }
  __shared__ float red[2][4];
  int wid = t >> 6, lane = t & 63;
  if (lane == 0) { red[0][wid] = s; red[1][wid] = s2; }
  __syncthreads();
  if (t == 0) {
    float ts  = red[0][0] + red[0][1] + red[0][2] + red[0][3];
    float ts2 = red[1][0] + red[1][1] + red[1][2] + red[1][3];
    float mean = ts * (1.0f / DIMM);
    float var  = ts2 * (1.0f / DIMM) - mean * mean;
    red[0][0] = mean;
    red[1][0] = rsqrtf(var + 1e-5f);
  }
  __syncthreads();
  float mean = red[0][0], rstd = red[1][0];
  __hip_bfloat16* orow = out + (size_t)row * DIMM;
  orow[t]       = __float2bfloat16((v0 - mean) * rstd * gam[t]       + bet[t]);
  orow[t + 256] = __float2bfloat16((v1 - mean) * rstd * gam[t + 256] + bet[t + 256]);
  orow[t + 512] = __float2bfloat16((v2 - mean) * rstd * gam[t + 512] + bet[t + 512]);
}

// ---------------- weight prep: W[K][N] f32 -> Wt[N][K] bf16 ----------------
__global__ __launch_bounds__(256) void wprep_kernel(
    const float* __restrict__ src, u16* __restrict__ dst,
    int ldsrc, int Krows, size_t sls, size_t dls) {
  __shared__ float tile[32][33];
  int l = blockIdx.z;
  int n0 = blockIdx.x * 32, k0 = blockIdx.y * 32;
  int tx = threadIdx.x & 31, ty = threadIdx.x >> 5;
  const float* s = src + (size_t)l * sls;
  u16* d = dst + (size_t)l * dls;
  #pragma unroll
  for (int i = 0; i < 4; ++i)
    tile[ty + i * 8][tx] = s[(size_t)(k0 + ty + i * 8) * ldsrc + n0 + tx];
  __syncthreads();
  #pragma unroll
  for (int i = 0; i < 4; ++i) {
    __hip_bfloat16 b = __float2bfloat16(tile[tx][ty + i * 8]);
    d[(size_t)(n0 + ty + i * 8) * Krows + k0 + tx] = *(u16*)&b;
  }
}

// ---------------- bf16 MFMA GEMM: counted-vmcnt pipeline (R11, best) ----------------
// A [M][K] bf16 (lda=K); Bt [N][K] bf16. Tile TBM x TBN, BK=32, 256 thr =
// 4 waves (2x2). Per step: vmcnt(G) [tile-t loads done, t+1 in flight] ->
// s_barrier -> ds_read -> lgkmcnt(0)+SBAR -> s_barrier [buf free] -> stage
// t+2 into freed buffer -> setprio(1) MFMA. No vmcnt(0) in steady state.
// 16-24 KB LDS, ~40-72 VGPR -> ~6 blocks/CU (TLP is the binding resource).
template<int TBM, int TBN>
__global__ __launch_bounds__(256) void gemm_bf16(
    const u16* __restrict__ A, const u16* __restrict__ Bt,
    const float* __restrict__ bias, const float* __restrict__ resid,
    void* __restrict__ Cv, int K, int ldc, int act, int cbf16) {
  constexpr int MFR = TBM / 32;
  constexpr int NFR = TBN / 32;
  constexpr int G = (TBM == 128 ? 2 : 1) + (TBN == 128 ? 2 : 1);  // gloads/thread/stage
  __shared__ u16 As[2][TBM * 32];
  __shared__ u16 Bs[2][TBN * 32];
  int tid = threadIdx.x;
  int wave = tid >> 6, lane = tid & 63;

  int lin = blockIdx.y * gridDim.x + blockIdx.x;
  int cpx = (gridDim.x * gridDim.y) >> 3;
  int swz = (lin & 7) * cpx + (lin >> 3);
  int by = swz % gridDim.y;               // M-tile fast within an XCD
  int bx = swz / gridDim.y;

  int bm = by * TBM, bn = bx * TBN;
  int wm = (wave >> 1) * (TBM / 2), wn = (wave & 1) * (TBN / 2);
  int fr = lane & 15, fq = lane >> 4;

  f32x4 acc[MFR][NFR];
  #pragma unroll
  for (int i = 0; i < MFR; ++i)
    #pragma unroll
    for (int j = 0; j < NFR; ++j) acc[i][j] = (f32x4){0.f, 0.f, 0.f, 0.f};

  int r0 = tid >> 2;
  int kb = ((tid & 3) ^ ((r0 >> 1) & 3)) * 8;
  const u16* aptr = A + (size_t)(bm + r0) * K + kb;
  const u16* bptr = Bt + (size_t)(bn + r0) * K + kb;
  int sA = (fq ^ ((fr >> 1) & 3)) * 8;

#define STAGE_TILE(buf) do {                                          \
    char* lA = (char*)(&As[buf][0]) + wave * 1024;                    \
    char* lB = (char*)(&Bs[buf][0]) + wave * 1024;                    \
    GLOAD16(aptr, lA);                                                \
    if constexpr (TBM == 128) GLOAD16(aptr + (size_t)64 * K, lA + 4096); \
    GLOAD16(bptr, lB);                                                \
    if constexpr (TBN == 128) GLOAD16(bptr + (size_t)64 * K, lB + 4096); \
    aptr += 32; bptr += 32;                                           \
  } while (0)

  const int nk = K >> 5;   // all call sites have K >= 768 -> nk >= 24 >= 2
  STAGE_TILE(0);
  STAGE_TILE(1);

  for (int t = 0; t < nk; ++t) {
    const int cur = t & 1;
    // tile t's own loads complete (tile t+1's G loads may remain in flight)
    if (t + 1 < nk) {
      if constexpr (G == 2) asm volatile("s_waitcnt vmcnt(2)" ::: "memory");
      else if constexpr (G == 3) asm volatile("s_waitcnt vmcnt(3)" ::: "memory");
      else asm volatile("s_waitcnt vmcnt(4)" ::: "memory");
    } else {
      VMDRAIN();
    }
    BAR();                 // all waves' tile-t stage landed in LDS
    bf16x8 af[MFR], bfr[NFR];
    #pragma unroll
    for (int m = 0; m < MFR; ++m)
      af[m] = *(const bf16x8*)&As[cur][(wm + m * 16 + fr) * 32 + sA];
    #pragma unroll
    for (int n = 0; n < NFR; ++n)
      bfr[n] = *(const bf16x8*)&Bs[cur][(wn + n * 16 + fr) * 32 + sA];
    asm volatile("s_waitcnt lgkmcnt(0)" ::: "memory");  // reads in regs
    SBAR();                // rule-18 fence: nothing hoists above the wait
    BAR();                 // all waves done reading buf cur -> safe to overwrite
    if (t + 2 < nk) STAGE_TILE(cur);   // stage tile t+2 into freed buffer
    PRIO(1);
    #pragma unroll
    for (int m = 0; m < MFR; ++m)
      #pragma unroll
      for (int n = 0; n < NFR; ++n)
        acc[m][n] = __builtin_amdgcn_mfma_f32_16x16x32_bf16(af[m], bfr[n], acc[m][n], 0, 0, 0);
    PRIO(0);
  }
#undef STAGE_TILE

  #pragma unroll
  for (int m = 0; m < MFR; ++m) {
    #pragma unroll
    for (int rr = 0; rr < 4; ++rr) {
      int row = bm + wm + m * 16 + fq * 4 + rr;
      #pragma unroll
      for (int n = 0; n < NFR; ++n) {
        int col = bn + wn + n * 16 + fr;
        float v = acc[m][n][rr];
        if (bias) v += bias[col];
        if (act) v = 0.5f * v * (1.0f + erff(v * 0.70710678118654752f));
        if (resid) v += resid[(size_t)row * ldc + col];
        if (cbf16) {
          __hip_bfloat16 b = __float2bfloat16(v);
          ((u16*)Cv)[(size_t)row * ldc + col] = *(u16*)&b;
        } else {
          ((float*)Cv)[(size_t)row * ldc + col] = v;
        }
      }
    }
  }
}

// ---------------- 256x256 logits GEMM: 4-deep counted-vmcnt + coalesced epilogue ----
// (round-12 4-deep pipeline. Round-16 diagnosis: NT stores dropped FETCH
// 390->255 MB but writes ran at 1.95 TB/s (31% peak) because the fragment
// layout emits 64B segments and NT bypasses L2 write-combining (WRITE_SIZE
// inflated 512->589 MB = partial-line overhead). Fix: per-wave LDS-transpose
// epilogue -> each row written as 256B contiguous per 4 lanes (full 128B
// lines) with regular stores. Slabs reuse retired A/B bufs 0/1 (laggard
// waves past the final barrier only read buf 3); stride-65 rows spread banks.)
__global__ __launch_bounds__(512, 1) void gemm256(
    const u16* __restrict__ A, const u16* __restrict__ Bt,
    const float* __restrict__ bias, float* __restrict__ C, int K, int ldc) {
  __shared__ __align__(16) char GL[131072];  // A bufs: [0,64K), B bufs: [64K,128K)
  const int tid = threadIdx.x;
  const int wave = tid >> 6, lane = tid & 63;
  const int fr = lane & 15, fq = lane >> 4;

  int lin = blockIdx.y * gridDim.x + blockIdx.x;
  int cpx = (gridDim.x * gridDim.y) >> 3;
  int swz = (lin & 7) * cpx + (lin >> 3);
  int by = swz % gridDim.y;               // M-tile fast within an XCD
  int bx = swz / gridDim.y;

  const int bm = by * 256, bn = bx * 256;
  const int wm = (wave >> 2) * 128, wn = (wave & 3) * 64;

  const int r_in = tid >> 2;
  const int g_swz = (tid & 3) ^ ((r_in >> 1) & 3);   // inverse-swizzled source granule
  const size_t a_base = (size_t)(bm + r_in) * K + g_swz * 8;
  const size_t b_base = (size_t)(bn + r_in) * K + g_swz * 8;
  const int lds_st = wave * 1024;

  const int sA = (fq ^ ((fr >> 1) & 3)) * 16;        // ds_read byte slot

  f32x4 acc[8][4];
  #pragma unroll
  for (int i = 0; i < 8; ++i)
    #pragma unroll
    for (int j = 0; j < 4; ++j) acc[i][j] = (f32x4){0.f, 0.f, 0.f, 0.f};

#define STG(s, b) do {                                                  \
    const u16* ga = A + a_base + (size_t)(s) * 32;                      \
    const u16* gb = Bt + b_base + (size_t)(s) * 32;                     \
    GLOAD16(ga,                   GL + (b) * 16384 + lds_st);           \
    GLOAD16(ga + (size_t)128 * K, GL + (b) * 16384 + 8192 + lds_st);    \
    GLOAD16(gb,                   GL + 65536 + (b) * 16384 + lds_st);   \
    GLOAD16(gb + (size_t)128 * K, GL + 65536 + (b) * 16384 + 8192 + lds_st); \
  } while (0)

  const int nk = K >> 5;   // K=768 -> 24
  STG(0, 0);
  STG(1, 1);
  STG(2, 2);

  for (int t = 0; t < nk; ++t) {
    const int buf = t & 3;
    // counted wait: tiles beyond t in flight = min(2, nk-1-t), 4 loads each
    if (t <= nk - 3)      asm volatile("s_waitcnt vmcnt(8)" ::: "memory");
    else if (t == nk - 2) asm volatile("s_waitcnt vmcnt(4)" ::: "memory");
    else                  VMDRAIN();
    BAR();   // all waves: tile t fully in LDS; all prior reads of (t+3)&3 done
    if (t + 3 < nk) STG(t + 3, (t + 3) & 3);
    bf16x8 aq[8], bq[4];
    const char* pa = GL + buf * 16384;
    const char* pb = GL + 65536 + buf * 16384;
    #pragma unroll
    for (int m = 0; m < 8; ++m)
      aq[m] = *(const bf16x8*)(pa + (wm + m * 16 + fr) * 64 + sA);
    #pragma unroll
    for (int n = 0; n < 4; ++n)
      bq[n] = *(const bf16x8*)(pb + (wn + n * 16 + fr) * 64 + sA);
    asm volatile("s_waitcnt lgkmcnt(0)" ::: "memory");
    SBAR();   // rule-18 fence
    PRIO(1);
    #pragma unroll
    for (int m = 0; m < 8; ++m)
      #pragma unroll
      for (int n = 0; n < 4; ++n)
        acc[m][n] = __builtin_amdgcn_mfma_f32_16x16x32_bf16(aq[m], bq[n], acc[m][n], 0, 0, 0);
    PRIO(0);
  }
#undef STG

  // ---- coalesced epilogue: per-wave LDS slab transpose, full-line stores ----
  // Slab = 16 rows x 64 f32, row stride 65 (fq bank-spread). Waves 0-3 use
  // A-buf0/1 region [0,32K); waves 4-7 use B-buf0/1 region [64K,96K). Safe:
  // any wave in the epilogue passed the final barrier; laggards only read
  // buf 3 ([48K,64K) / [112K,128K)). No barriers needed (wave-private slab).
  {
    float* slab = (float*)(wave < 4 ? GL + wave * 8192
                                    : GL + 65536 + (wave - 4) * 8192);
    const int r2 = lane >> 2, c2 = (lane & 3) * 16;
    float bias_v[4];
    #pragma unroll
    for (int n = 0; n < 4; ++n) bias_v[n] = bias[bn + wn + n * 16 + fr];
    #pragma unroll
    for (int m = 0; m < 8; ++m) {
      asm volatile("s_waitcnt lgkmcnt(0)" ::: "memory");  // prior slab reads done
      SBAR();
      #pragma unroll
      for (int n = 0; n < 4; ++n)
        #pragma unroll
        for (int rr = 0; rr < 4; ++rr)
          slab[(fq * 4 + rr) * 65 + n * 16 + fr] = acc[m][n][rr] + bias_v[n];
      asm volatile("s_waitcnt lgkmcnt(0)" ::: "memory");  // writes visible in-wave
      SBAR();
      f32x4 vv[4];
      #pragma unroll
      for (int j = 0; j < 4; ++j)
        vv[j] = *(const f32x4*)&slab[r2 * 65 + c2 + j * 4];
      asm volatile("s_waitcnt lgkmcnt(0)" ::: "memory");
      SBAR();
      float* cp = &C[(size_t)(bm + wm + m * 16 + r2) * ldc + bn + wn + c2];
      #pragma unroll
      for (int j = 0; j < 4; ++j)
        *(f32x4*)(cp + j * 4) = vv[j];
    }
  }
}

// ---------------- MFMA local attention (values == keys) ----------------
// Block = (bucket w, head hd), 256 thr = 4 waves; wave owns 32 query rows.
// LDS: Kl[256 keys][64 d] bf16 (XOR-swizzled granules), Kt[64 d][256 j]
// (transposed copy for the PV B-operand), Pw[wave][32 rows][256 j] bf16 P.
// Swizzle: 16B granule g of row r stored at slot g^(r&7) (both write & read).
// Zero keys for bucket 0 staged as 0 -> logit 0 kept in denominator (= ref).
// Causal: key j visible iff j <= r + 128.
__global__ __launch_bounds__(256, 1) void attn_mfma(
    const u16* __restrict__ QK, u16* __restrict__ CTX) {
  __shared__ __align__(16) char LDS[131072];
  char* Kl = LDS;                       // 32 KiB
  char* Kt = LDS + 32768;               // 32 KiB
  const int w = blockIdx.x, hd = blockIdx.y;
  const int tid = threadIdx.x;
  const int wave = tid >> 6, lane = tid & 63;
  const int fr = lane & 15, fq = lane >> 4;
  char* Pw = LDS + 65536 + wave * 16384;  // 16 KiB per wave

  // ---- stage K row j=tid (+ transposed copy) ----
  {
    const int j = tid;
    const int p = (w - 1) * WWIN + j;
    bf16x8 kv[8];
    if (p >= 0) {
      const bf16x8* src = (const bf16x8*)(QK + (size_t)p * QKLD + DIMM + hd * DH);
      #pragma unroll
      for (int g = 0; g < 8; ++g) kv[g] = src[g];
    } else {
      #pragma unroll
      for (int g = 0; g < 8; ++g) kv[g] = (bf16x8){0, 0, 0, 0, 0, 0, 0, 0};
    }
    #pragma unroll
    for (int g = 0; g < 8; ++g)
      *(bf16x8*)(Kl + j * 128 + ((g ^ (j & 7)) * 16)) = kv[g];
    #pragma unroll
    for (int g = 0; g < 8; ++g)
      #pragma unroll
      for (int e = 0; e < 8; ++e) {
        const int d = g * 8 + e;
        *(u16*)(Kt + d * 512 + (((j >> 3) ^ (d & 7)) * 16) + ((j & 7) * 2)) =
            (u16)kv[g][e];
      }
  }

  // ---- Q fragments straight from global ----
  bf16x8 aq[2][2];
  #pragma unroll
  for (int m = 0; m < 2; ++m)
    #pragma unroll
    for (int kk = 0; kk < 2; ++kk)
      aq[m][kk] = *(const bf16x8*)(QK +
          (size_t)(w * WWIN + wave * 32 + m * 16 + fr) * QKLD + hd * DH + kk * 32 + fq * 8);

  __syncthreads();

  // ---- S = Q K^T : per wave 32 rows x 256 cols ----
  f32x4 sacc[2][16];
  #pragma unroll
  for (int m = 0; m < 2; ++m)
    #pragma unroll
    for (int n = 0; n < 16; ++n) sacc[m][n] = (f32x4){0.f, 0.f, 0.f, 0.f};
  #pragma unroll
  for (int n = 0; n < 16; ++n) {
    #pragma unroll
    for (int kk = 0; kk < 2; ++kk) {
      bf16x8 bk = *(const bf16x8*)(Kl + (n * 16 + fr) * 128 +
                                   (((kk * 4 + fq) ^ (fr & 7)) * 16));
      #pragma unroll
      for (int m = 0; m < 2; ++m)
        sacc[m][n] = __builtin_amdgcn_mfma_f32_16x16x32_bf16(aq[m][kk], bk, sacc[m][n], 0, 0, 0);
    }
  }

  // ---- masked softmax (row-wise over 256; values=keys) ----
  float inv_[2][4];
  #pragma unroll
  for (int m = 0; m < 2; ++m) {
    #pragma unroll
    for (int rr = 0; rr < 4; ++rr) {
      const int r = wave * 32 + m * 16 + fq * 4 + rr;   // bucket-local query row
      float pv[16];
      float mx = NEG_MAX;
      #pragma unroll
      for (int n = 0; n < 16; ++n) {
        const int j = n * 16 + fr;
        float s = sacc[m][n][rr] * 0.125f;
        bool vis = (j <= r + 128);
        pv[n] = vis ? s : NEG_MAX;
        if (vis) mx = fmaxf(mx, s);
      }
      #pragma unroll
      for (int o = 1; o < 16; o <<= 1) mx = fmaxf(mx, __shfl_xor(mx, o));
      float sum = 0.f;
      #pragma unroll
      for (int n = 0; n < 16; ++n) {
        float p = (pv[n] != NEG_MAX) ? __expf(pv[n] - mx) : 0.f;
        pv[n] = p;
        sum += p;
      }
      #pragma unroll
      for (int o = 1; o < 16; o <<= 1) sum += __shfl_xor(sum, o);
      inv_[m][rr] = 1.0f / sum;
      const int rl = m * 16 + fq * 4 + rr;              // 0..31 within wave
      #pragma unroll
      for (int n = 0; n < 16; ++n) {
        __hip_bfloat16 b = __float2bfloat16(pv[n]);
        const int gj = n * 2 + (fr >> 3);
        *(u16*)(Pw + rl * 512 + ((gj ^ (rl & 7)) * 16) + ((fr & 7) * 2)) = *(u16*)&b;
      }
    }
  }
  __syncthreads();

  // ---- O = P K (values == keys) ----
  f32x4 oacc[2][4];
  #pragma unroll
  for (int m = 0; m < 2; ++m)
    #pragma unroll
    for (int nd = 0; nd < 4; ++nd) oacc[m][nd] = (f32x4){0.f, 0.f, 0.f, 0.f};
  #pragma unroll
  for (int kc = 0; kc < 8; ++kc) {
    const int slot = ((kc * 4 + fq) ^ (fr & 7)) * 16;
    bf16x8 pa[2];
    #pragma unroll
    for (int m = 0; m < 2; ++m)
      pa[m] = *(const bf16x8*)(Pw + (m * 16 + fr) * 512 + slot);
    #pragma unroll
    for (int nd = 0; nd < 4; ++nd) {
      bf16x8 kb = *(const bf16x8*)(Kt + (nd * 16 + fr) * 512 + slot);
      #pragma unroll
      for (int m = 0; m < 2; ++m)
        oacc[m][nd] = __builtin_amdgcn_mfma_f32_16x16x32_bf16(pa[m], kb, oacc[m][nd], 0, 0, 0);
    }
  }

  // ---- epilogue ----
  #pragma unroll
  for (int m = 0; m < 2; ++m)
    #pragma unroll
    for (int nd = 0; nd < 4; ++nd)
      #pragma unroll
      for (int rr = 0; rr < 4; ++rr) {
        const int row = w * WWIN + wave * 32 + m * 16 + fq * 4 + rr;
        const int col = hd * DH + nd * 16 + fr;
        __hip_bfloat16 b = __float2bfloat16(oacc[m][nd][rr] * inv_[m][rr]);
        CTX[(size_t)row * DIMM + col] = *(u16*)&b;
      }
}

// ---------------- launch ----------------
extern "C" void kernel_launch(void* const* d_in, const int* in_sizes, int n_in,
                              void* d_out, int out_size, void* d_ws, size_t ws_size,
                              hipStream_t stream) {
  const int*   x         = (const int*)d_in[0];
  const float* token_emb = (const float*)d_in[1];
  const float* pos_emb   = (const float*)d_in[2];
  // d_in[3..14]: global-transformer params — dead (fully masked), unused.
  const float* ln1_g = (const float*)d_in[15];
  const float* ln1_b = (const float*)d_in[16];
  const float* wq    = (const float*)d_in[17];
  const float* wkv   = (const float*)d_in[18];
  const float* wo    = (const float*)d_in[19];
  const float* bo    = (const float*)d_in[20];
  const float* ln2_g = (const float*)d_in[21];
  const float* ln2_b = (const float*)d_in[22];
  const float* w1    = (const float*)d_in[23];
  const float* b1    = (const float*)d_in[24];
  const float* w2    = (const float*)d_in[25];
  const float* b2    = (const float*)d_in[26];
  const float* f_ln_g = (const float*)d_in[27];
  const float* f_ln_b = (const float*)d_in[28];
  const float* w_logits = (const float*)d_in[29];
  const float* b_logits = (const float*)d_in[30];
  float* out = (float*)d_out;

  // --- scratch in d_out (fully rewritten by final logits GEMM) ---
  char* ob = (char*)d_out;
  float* h    = (float*)(ob + 0);          // 12.58 MB f32 residual stream
  u16* qk     = (u16*)(ob + 12582912);     // 12.58 MB bf16 [4096][1536]
  u16* ctx    = (u16*)(ob + 25165824);     // 6.29 MB bf16
  u16* mid    = (u16*)(ob + 31457280);     // 25.17 MB bf16 FFN mid
  u16* warena = (u16*)(ob + 56623104);     // 51.9 MB bf16 transposed weights
  const size_t WQ_SZ = (size_t)DIMM * DIMM;     // 589824
  const size_t W1_SZ = (size_t)DIMM * FFDIM;    // 2359296
  const size_t LW = 3 * WQ_SZ + 2 * W1_SZ;
  u16* qkw_t = warena;                 // [1536][768]: rows 0..767 = wq^T, 768.. = wk^T
  u16* wo_t  = warena + 2 * WQ_SZ;
  u16* w1_t  = warena + 3 * WQ_SZ;
  u16* w2_t  = warena + 3 * WQ_SZ + W1_SZ;

  // --- scratch in d_ws (live during final logits GEMM) ---
  u16* wlog_t = (u16*)d_ws;                                           // 49.15 MB
  __hip_bfloat16* lnbuf = (__hip_bfloat16*)((char*)d_ws + 49152000);  // 6.29 MB

  // ---- weight prep ----
  wprep_kernel<<<dim3(24, 24, 4), 256, 0, stream>>>(wq,  qkw_t,         DIMM,   DIMM,  WQ_SZ,   LW);
  wprep_kernel<<<dim3(24, 24, 4), 256, 0, stream>>>(wkv, qkw_t + WQ_SZ, 2*DIMM, DIMM,  2*WQ_SZ, LW);
  wprep_kernel<<<dim3(24, 24, 4), 256, 0, stream>>>(wo,  wo_t,          DIMM,   DIMM,  WQ_SZ,   LW);
  wprep_kernel<<<dim3(96, 24, 4), 256, 0, stream>>>(w1,  w1_t,          FFDIM,  DIMM,  W1_SZ,   LW);
  wprep_kernel<<<dim3(24, 96, 4), 256, 0, stream>>>(w2,  w2_t,          DIMM,   FFDIM, W1_SZ,   LW);
  wprep_kernel<<<dim3(1000, 24, 1), 256, 0, stream>>>(w_logits, wlog_t, NTOK, DIMM, 0, 0);

  embed_kernel<<<SEQLEN, 256, 0, stream>>>(x, token_emb, pos_emb, h);

  for (int l = 0; l < NDEPTH; ++l) {
    ln_kernel<<<SEQLEN, 256, 0, stream>>>(h, ln1_g + l * DIMM, ln1_b + l * DIMM, lnbuf);
    gemm_bf16<64, 128><<<dim3(12, 64), 256, 0, stream>>>(
        (const u16*)lnbuf, qkw_t + l * LW, nullptr, nullptr, qk, DIMM, QKLD, 0, 1);
    attn_mfma<<<dim3(NBUCK, NHEADS), 256, 0, stream>>>(qk, ctx);
    gemm_bf16<64, 64><<<dim3(12, 64), 256, 0, stream>>>(
        ctx, wo_t + l * LW, bo + l * DIMM, h, h, DIMM, DIMM, 0, 0);
    ln_kernel<<<SEQLEN, 256, 0, stream>>>(h, ln2_g + l * DIMM, ln2_b + l * DIMM, lnbuf);
    gemm_bf16<64, 128><<<dim3(24, 64), 256, 0, stream>>>(
        (const u16*)lnbuf, w1_t + l * LW, b1 + l * FFDIM, nullptr, mid, DIMM, FFDIM, 1, 1);
    gemm_bf16<64, 64><<<dim3(12, 64), 256, 0, stream>>>(
        mid, w2_t + l * LW, b2 + l * DIMM, h, h, FFDIM, DIMM, 0, 0);
  }

  ln_kernel<<<SEQLEN, 256, 0, stream>>>(h, f_ln_g, f_ln_b, lnbuf);
  gemm256<<<dim3(NTOK / 256, SEQLEN / 256), 512, 0, stream>>>(
      (const u16*)lnbuf, wlog_t, b_logits, out, DIMM, NTOK);
}

// Round 19
// 1130.074 us; speedup vs baseline: 1.0888x; 1.0888x over previous
//
#include <hip/hip_runtime.h>
#include <hip/hip_bf16.h>

// Poolformer forward, bf16-MFMA GEMMs + MFMA flash attention.
// Dead code proofs (reference quirks we exploit):
//  1. m_glob = triu(ones((32,31)), k=-97) is all-True -> ALL global keys masked
//     -> softmax weight exactly 0 -> global transformer branch skipped.
//  2. v2 = k2 in local_attn: attention VALUES are the KEYS -> v-half of x@wkv dead.
// Scratch: d_ws holds only buffers live during the final logits GEMM; all other
// intermediates live in d_out (fully rewritten by the logits GEMM every call).
// NOTE round-18 lesson: the wave-per-row LN variant caused a sporadic
// post-timing divergence (timing-sensitive race, root cause unproven) ->
// reverted to this twice-validated round-16 configuration.

#define DIMM   768
#define SEQLEN 4096
#define NHEADS 12
#define DH     64
#define WWIN   128
#define NBUCK  32
#define NDEPTH 4
#define FFDIM  3072
#define NTOK   32000
#define QKLD   1536
#define NEG_MAX (-3.402823466e38f)

typedef unsigned short u16;
typedef __attribute__((ext_vector_type(8))) short bf16x8;
typedef __attribute__((ext_vector_type(4))) float f32x4;

#define GLOAD16(gp, lp) \
  __builtin_amdgcn_global_load_lds((const __attribute__((address_space(1))) void*)(gp), \
                                   (__attribute__((address_space(3))) void*)(lp), 16, 0, 0)

#define BAR()      __builtin_amdgcn_s_barrier()
#define SBAR()     __builtin_amdgcn_sched_barrier(0)
#define PRIO(x)    __builtin_amdgcn_s_setprio(x)
#define VMDRAIN()  asm volatile("s_waitcnt vmcnt(0)" ::: "memory")

// ---------------- embed ----------------
__global__ __launch_bounds__(256) void embed_kernel(
    const int* __restrict__ x, const float* __restrict__ tok,
    const float* __restrict__ pos, float* __restrict__ h) {
  int row = blockIdx.x;
  int t = threadIdx.x;
  int tk = x[row];
  const float* te = tok + (size_t)tk * DIMM;
  const float* pe = pos + (size_t)row * DIMM;
  float* hr = h + (size_t)row * DIMM;
  hr[t]       = te[t]       + pe[t];
  hr[t + 256] = te[t + 256] + pe[t + 256];
  hr[t + 512] = te[t + 512] + pe[t + 512];
}

// ---------------- layernorm: f32 in, bf16 out (round-16 proven) ----------------
__global__ __launch_bounds__(256) void ln_kernel(
    const float* __restrict__ in, const float* __restrict__ gam,
    const float* __restrict__ bet, __hip_bfloat16* __restrict__ out) {
  int row = blockIdx.x;
  int t = threadIdx.x;
  const float* xr = in + (size_t)row * DIMM;
  float v0 = xr[t], v1 = xr[t + 256], v2 = xr[t + 512];
  float s  = v0 + v1 + v2;
  float s2 = v0 * v0 + v1 * v1 + v2 * v2;
  #pragma unroll
  for (int o = 32; o > 0; o >>= 1) {
    s  += __shfl_down(s, o);
    s2 += __shfl_down(s2, o);
  }
  __shared__ float red[2][4];
  int wid = t >> 6, lane = t & 63;
  if (lane == 0) { red[0][wid] = s; red[1][wid] = s2; }
  __syncthreads();
  if (t == 0) {
    float ts  = red[0][0] + red[0][1] + red[0][2] + red[0][3];
    float ts2 = red[1][0] + red[1][1] + red[1][2] + red[1][3];
    float mean = ts * (1.0f / DIMM);
    float var  = ts2 * (1.0f / DIMM) - mean * mean;
    red[0][0] = mean;
    red[1][0] = rsqrtf(var + 1e-5f);
  }
  __syncthreads();
  float mean = red[0][0], rstd = red[1][0];
  __hip_bfloat16* orow = out + (size_t)row * DIMM;
  orow[t]       = __float2bfloat16((v0 - mean) * rstd * gam[t]       + bet[t]);
  orow[t + 256] = __float2bfloat16((v1 - mean) * rstd * gam[t + 256] + bet[t + 256]);
  orow[t + 512] = __float2bfloat16((v2 - mean) * rstd * gam[t + 512] + bet[t + 512]);
}

// ---------------- weight prep: W[K][N] f32 -> Wt[N][K] bf16 ----------------
__global__ __launch_bounds__(256) void wprep_kernel(
    const float* __restrict__ src, u16* __restrict__ dst,
    int ldsrc, int Krows, size_t sls, size_t dls) {
  __shared__ float tile[32][33];
  int l = blockIdx.z;
  int n0 = blockIdx.x * 32, k0 = blockIdx.y * 32;
  int tx = threadIdx.x & 31, ty = threadIdx.x >> 5;
  const float* s = src + (size_t)l * sls;
  u16* d = dst + (size_t)l * dls;
  #pragma unroll
  for (int i = 0; i < 4; ++i)
    tile[ty + i * 8][tx] = s[(size_t)(k0 + ty + i * 8) * ldsrc + n0 + tx];
  __syncthreads();
  #pragma unroll
  for (int i = 0; i < 4; ++i) {
    __hip_bfloat16 b = __float2bfloat16(tile[tx][ty + i * 8]);
    d[(size_t)(n0 + ty + i * 8) * Krows + k0 + tx] = *(u16*)&b;
  }
}

// ---------------- bf16 MFMA GEMM: counted-vmcnt pipeline (R11, best) ----------------
// A [M][K] bf16 (lda=K); Bt [N][K] bf16. Tile TBM x TBN, BK=32, 256 thr =
// 4 waves (2x2). Per step: vmcnt(G) [tile-t loads done, t+1 in flight] ->
// s_barrier -> ds_read -> lgkmcnt(0)+SBAR -> s_barrier [buf free] -> stage
// t+2 into freed buffer -> setprio(1) MFMA. No vmcnt(0) in steady state.
// 16-24 KB LDS, ~40-72 VGPR -> ~6 blocks/CU (TLP is the binding resource).
template<int TBM, int TBN>
__global__ __launch_bounds__(256) void gemm_bf16(
    const u16* __restrict__ A, const u16* __restrict__ Bt,
    const float* __restrict__ bias, const float* __restrict__ resid,
    void* __restrict__ Cv, int K, int ldc, int act, int cbf16) {
  constexpr int MFR = TBM / 32;
  constexpr int NFR = TBN / 32;
  constexpr int G = (TBM == 128 ? 2 : 1) + (TBN == 128 ? 2 : 1);  // gloads/thread/stage
  __shared__ u16 As[2][TBM * 32];
  __shared__ u16 Bs[2][TBN * 32];
  int tid = threadIdx.x;
  int wave = tid >> 6, lane = tid & 63;

  int lin = blockIdx.y * gridDim.x + blockIdx.x;
  int cpx = (gridDim.x * gridDim.y) >> 3;
  int swz = (lin & 7) * cpx + (lin >> 3);
  int by = swz % gridDim.y;               // M-tile fast within an XCD
  int bx = swz / gridDim.y;

  int bm = by * TBM, bn = bx * TBN;
  int wm = (wave >> 1) * (TBM / 2), wn = (wave & 1) * (TBN / 2);
  int fr = lane & 15, fq = lane >> 4;

  f32x4 acc[MFR][NFR];
  #pragma unroll
  for (int i = 0; i < MFR; ++i)
    #pragma unroll
    for (int j = 0; j < NFR; ++j) acc[i][j] = (f32x4){0.f, 0.f, 0.f, 0.f};

  int r0 = tid >> 2;
  int kb = ((tid & 3) ^ ((r0 >> 1) & 3)) * 8;
  const u16* aptr = A + (size_t)(bm + r0) * K + kb;
  const u16* bptr = Bt + (size_t)(bn + r0) * K + kb;
  int sA = (fq ^ ((fr >> 1) & 3)) * 8;

#define STAGE_TILE(buf) do {                                          \
    char* lA = (char*)(&As[buf][0]) + wave * 1024;                    \
    char* lB = (char*)(&Bs[buf][0]) + wave * 1024;                    \
    GLOAD16(aptr, lA);                                                \
    if constexpr (TBM == 128) GLOAD16(aptr + (size_t)64 * K, lA + 4096); \
    GLOAD16(bptr, lB);                                                \
    if constexpr (TBN == 128) GLOAD16(bptr + (size_t)64 * K, lB + 4096); \
    aptr += 32; bptr += 32;                                           \
  } while (0)

  const int nk = K >> 5;   // all call sites have K >= 768 -> nk >= 24 >= 2
  STAGE_TILE(0);
  STAGE_TILE(1);

  for (int t = 0; t < nk; ++t) {
    const int cur = t & 1;
    // tile t's own loads complete (tile t+1's G loads may remain in flight)
    if (t + 1 < nk) {
      if constexpr (G == 2) asm volatile("s_waitcnt vmcnt(2)" ::: "memory");
      else if constexpr (G == 3) asm volatile("s_waitcnt vmcnt(3)" ::: "memory");
      else asm volatile("s_waitcnt vmcnt(4)" ::: "memory");
    } else {
      VMDRAIN();
    }
    BAR();                 // all waves' tile-t stage landed in LDS
    bf16x8 af[MFR], bfr[NFR];
    #pragma unroll
    for (int m = 0; m < MFR; ++m)
      af[m] = *(const bf16x8*)&As[cur][(wm + m * 16 + fr) * 32 + sA];
    #pragma unroll
    for (int n = 0; n < NFR; ++n)
      bfr[n] = *(const bf16x8*)&Bs[cur][(wn + n * 16 + fr) * 32 + sA];
    asm volatile("s_waitcnt lgkmcnt(0)" ::: "memory");  // reads in regs
    SBAR();                // rule-18 fence: nothing hoists above the wait
    BAR();                 // all waves done reading buf cur -> safe to overwrite
    if (t + 2 < nk) STAGE_TILE(cur);   // stage tile t+2 into freed buffer
    PRIO(1);
    #pragma unroll
    for (int m = 0; m < MFR; ++m)
      #pragma unroll
      for (int n = 0; n < NFR; ++n)
        acc[m][n] = __builtin_amdgcn_mfma_f32_16x16x32_bf16(af[m], bfr[n], acc[m][n], 0, 0, 0);
    PRIO(0);
  }
#undef STAGE_TILE

  #pragma unroll
  for (int m = 0; m < MFR; ++m) {
    #pragma unroll
    for (int rr = 0; rr < 4; ++rr) {
      int row = bm + wm + m * 16 + fq * 4 + rr;
      #pragma unroll
      for (int n = 0; n < NFR; ++n) {
        int col = bn + wn + n * 16 + fr;
        float v = acc[m][n][rr];
        if (bias) v += bias[col];
        if (act) v = 0.5f * v * (1.0f + erff(v * 0.70710678118654752f));
        if (resid) v += resid[(size_t)row * ldc + col];
        if (cbf16) {
          __hip_bfloat16 b = __float2bfloat16(v);
          ((u16*)Cv)[(size_t)row * ldc + col] = *(u16*)&b;
        } else {
          ((float*)Cv)[(size_t)row * ldc + col] = v;
        }
      }
    }
  }
}

// ---------------- 256x256 logits GEMM: 4-deep counted-vmcnt + NT stores ----------------
// (round-16 config — session best. NT stores keep the 512 MB never-re-read C
// stream out of L2 so it stops evicting B panels (FETCH 390->255 MB).)
__global__ __launch_bounds__(512, 1) void gemm256(
    const u16* __restrict__ A, const u16* __restrict__ Bt,
    const float* __restrict__ bias, float* __restrict__ C, int K, int ldc) {
  __shared__ __align__(16) char GL[131072];  // A bufs: [0,64K), B bufs: [64K,128K)
  const int tid = threadIdx.x;
  const int wave = tid >> 6, lane = tid & 63;
  const int fr = lane & 15, fq = lane >> 4;

  int lin = blockIdx.y * gridDim.x + blockIdx.x;
  int cpx = (gridDim.x * gridDim.y) >> 3;
  int swz = (lin & 7) * cpx + (lin >> 3);
  int by = swz % gridDim.y;               // M-tile fast within an XCD
  int bx = swz / gridDim.y;

  const int bm = by * 256, bn = bx * 256;
  const int wm = (wave >> 2) * 128, wn = (wave & 3) * 64;

  const int r_in = tid >> 2;
  const int g_swz = (tid & 3) ^ ((r_in >> 1) & 3);   // inverse-swizzled source granule
  const size_t a_base = (size_t)(bm + r_in) * K + g_swz * 8;
  const size_t b_base = (size_t)(bn + r_in) * K + g_swz * 8;
  const int lds_st = wave * 1024;

  const int sA = (fq ^ ((fr >> 1) & 3)) * 16;        // ds_read byte slot

  f32x4 acc[8][4];
  #pragma unroll
  for (int i = 0; i < 8; ++i)
    #pragma unroll
    for (int j = 0; j < 4; ++j) acc[i][j] = (f32x4){0.f, 0.f, 0.f, 0.f};

#define STG(s, b) do {                                                  \
    const u16* ga = A + a_base + (size_t)(s) * 32;                      \
    const u16* gb = Bt + b_base + (size_t)(s) * 32;                     \
    GLOAD16(ga,                   GL + (b) * 16384 + lds_st);           \
    GLOAD16(ga + (size_t)128 * K, GL + (b) * 16384 + 8192 + lds_st);    \
    GLOAD16(gb,                   GL + 65536 + (b) * 16384 + lds_st);   \
    GLOAD16(gb + (size_t)128 * K, GL + 65536 + (b) * 16384 + 8192 + lds_st); \
  } while (0)

  const int nk = K >> 5;   // K=768 -> 24
  STG(0, 0);
  STG(1, 1);
  STG(2, 2);

  for (int t = 0; t < nk; ++t) {
    const int buf = t & 3;
    // counted wait: tiles beyond t in flight = min(2, nk-1-t), 4 loads each
    if (t <= nk - 3)      asm volatile("s_waitcnt vmcnt(8)" ::: "memory");
    else if (t == nk - 2) asm volatile("s_waitcnt vmcnt(4)" ::: "memory");
    else                  VMDRAIN();
    BAR();   // all waves: tile t fully in LDS; all prior reads of (t+3)&3 done
    if (t + 3 < nk) STG(t + 3, (t + 3) & 3);
    bf16x8 aq[8], bq[4];
    const char* pa = GL + buf * 16384;
    const char* pb = GL + 65536 + buf * 16384;
    #pragma unroll
    for (int m = 0; m < 8; ++m)
      aq[m] = *(const bf16x8*)(pa + (wm + m * 16 + fr) * 64 + sA);
    #pragma unroll
    for (int n = 0; n < 4; ++n)
      bq[n] = *(const bf16x8*)(pb + (wn + n * 16 + fr) * 64 + sA);
    asm volatile("s_waitcnt lgkmcnt(0)" ::: "memory");
    SBAR();   // rule-18 fence
    PRIO(1);
    #pragma unroll
    for (int m = 0; m < 8; ++m)
      #pragma unroll
      for (int n = 0; n < 4; ++n)
        acc[m][n] = __builtin_amdgcn_mfma_f32_16x16x32_bf16(aq[m], bq[n], acc[m][n], 0, 0, 0);
    PRIO(0);
  }
#undef STG

  #pragma unroll
  for (int m = 0; m < 8; ++m) {
    #pragma unroll
    for (int rr = 0; rr < 4; ++rr) {
      int row = bm + wm + m * 16 + fq * 4 + rr;
      #pragma unroll
      for (int n = 0; n < 4; ++n) {
        int col = bn + wn + n * 16 + fr;
        // NT store: C is never re-read; keep the 512 MB write stream out of L2
        __builtin_nontemporal_store(acc[m][n][rr] + bias[col],
                                    &C[(size_t)row * ldc + col]);
      }
    }
  }
}

// ---------------- MFMA local attention (values == keys) ----------------
// Block = (bucket w, head hd), 256 thr = 4 waves; wave owns 32 query rows.
// LDS: Kl[256 keys][64 d] bf16 (XOR-swizzled granules), Kt[64 d][256 j]
// (transposed copy for the PV B-operand), Pw[wave][32 rows][256 j] bf16 P.
// Swizzle: 16B granule g of row r stored at slot g^(r&7) (both write & read).
// Zero keys for bucket 0 staged as 0 -> logit 0 kept in denominator (= ref).
// Causal: key j visible iff j <= r + 128.
__global__ __launch_bounds__(256, 1) void attn_mfma(
    const u16* __restrict__ QK, u16* __restrict__ CTX) {
  __shared__ __align__(16) char LDS[131072];
  char* Kl = LDS;                       // 32 KiB
  char* Kt = LDS + 32768;               // 32 KiB
  const int w = blockIdx.x, hd = blockIdx.y;
  const int tid = threadIdx.x;
  const int wave = tid >> 6, lane = tid & 63;
  const int fr = lane & 15, fq = lane >> 4;
  char* Pw = LDS + 65536 + wave * 16384;  // 16 KiB per wave

  // ---- stage K row j=tid (+ transposed copy) ----
  {
    const int j = tid;
    const int p = (w - 1) * WWIN + j;
    bf16x8 kv[8];
    if (p >= 0) {
      const bf16x8* src = (const bf16x8*)(QK + (size_t)p * QKLD + DIMM + hd * DH);
      #pragma unroll
      for (int g = 0; g < 8; ++g) kv[g] = src[g];
    } else {
      #pragma unroll
      for (int g = 0; g < 8; ++g) kv[g] = (bf16x8){0, 0, 0, 0, 0, 0, 0, 0};
    }
    #pragma unroll
    for (int g = 0; g < 8; ++g)
      *(bf16x8*)(Kl + j * 128 + ((g ^ (j & 7)) * 16)) = kv[g];
    #pragma unroll
    for (int g = 0; g < 8; ++g)
      #pragma unroll
      for (int e = 0; e < 8; ++e) {
        const int d = g * 8 + e;
        *(u16*)(Kt + d * 512 + (((j >> 3) ^ (d & 7)) * 16) + ((j & 7) * 2)) =
            (u16)kv[g][e];
      }
  }

  // ---- Q fragments straight from global ----
  bf16x8 aq[2][2];
  #pragma unroll
  for (int m = 0; m < 2; ++m)
    #pragma unroll
    for (int kk = 0; kk < 2; ++kk)
      aq[m][kk] = *(const bf16x8*)(QK +
          (size_t)(w * WWIN + wave * 32 + m * 16 + fr) * QKLD + hd * DH + kk * 32 + fq * 8);

  __syncthreads();

  // ---- S = Q K^T : per wave 32 rows x 256 cols ----
  f32x4 sacc[2][16];
  #pragma unroll
  for (int m = 0; m < 2; ++m)
    #pragma unroll
    for (int n = 0; n < 16; ++n) sacc[m][n] = (f32x4){0.f, 0.f, 0.f, 0.f};
  #pragma unroll
  for (int n = 0; n < 16; ++n) {
    #pragma unroll
    for (int kk = 0; kk < 2; ++kk) {
      bf16x8 bk = *(const bf16x8*)(Kl + (n * 16 + fr) * 128 +
                                   (((kk * 4 + fq) ^ (fr & 7)) * 16));
      #pragma unroll
      for (int m = 0; m < 2; ++m)
        sacc[m][n] = __builtin_amdgcn_mfma_f32_16x16x32_bf16(aq[m][kk], bk, sacc[m][n], 0, 0, 0);
    }
  }

  // ---- masked softmax (row-wise over 256; values=keys) ----
  float inv_[2][4];
  #pragma unroll
  for (int m = 0; m < 2; ++m) {
    #pragma unroll
    for (int rr = 0; rr < 4; ++rr) {
      const int r = wave * 32 + m * 16 + fq * 4 + rr;   // bucket-local query row
      float pv[16];
      float mx = NEG_MAX;
      #pragma unroll
      for (int n = 0; n < 16; ++n) {
        const int j = n * 16 + fr;
        float s = sacc[m][n][rr] * 0.125f;
        bool vis = (j <= r + 128);
        pv[n] = vis ? s : NEG_MAX;
        if (vis) mx = fmaxf(mx, s);
      }
      #pragma unroll
      for (int o = 1; o < 16; o <<= 1) mx = fmaxf(mx, __shfl_xor(mx, o));
      float sum = 0.f;
      #pragma unroll
      for (int n = 0; n < 16; ++n) {
        float p = (pv[n] != NEG_MAX) ? __expf(pv[n] - mx) : 0.f;
        pv[n] = p;
        sum += p;
      }
      #pragma unroll
      for (int o = 1; o < 16; o <<= 1) sum += __shfl_xor(sum, o);
      inv_[m][rr] = 1.0f / sum;
      const int rl = m * 16 + fq * 4 + rr;              // 0..31 within wave
      #pragma unroll
      for (int n = 0; n < 16; ++n) {
        __hip_bfloat16 b = __float2bfloat16(pv[n]);
        const int gj = n * 2 + (fr >> 3);
        *(u16*)(Pw + rl * 512 + ((gj ^ (rl & 7)) * 16) + ((fr & 7) * 2)) = *(u16*)&b;
      }
    }
  }
  __syncthreads();

  // ---- O = P K (values == keys) ----
  f32x4 oacc[2][4];
  #pragma unroll
  for (int m = 0; m < 2; ++m)
    #pragma unroll
    for (int nd = 0; nd < 4; ++nd) oacc[m][nd] = (f32x4){0.f, 0.f, 0.f, 0.f};
  #pragma unroll
  for (int kc = 0; kc < 8; ++kc) {
    const int slot = ((kc * 4 + fq) ^ (fr & 7)) * 16;
    bf16x8 pa[2];
    #pragma unroll
    for (int m = 0; m < 2; ++m)
      pa[m] = *(const bf16x8*)(Pw + (m * 16 + fr) * 512 + slot);
    #pragma unroll
    for (int nd = 0; nd < 4; ++nd) {
      bf16x8 kb = *(const bf16x8*)(Kt + (nd * 16 + fr) * 512 + slot);
      #pragma unroll
      for (int m = 0; m < 2; ++m)
        oacc[m][nd] = __builtin_amdgcn_mfma_f32_16x16x32_bf16(pa[m], kb, oacc[m][nd], 0, 0, 0);
    }
  }

  // ---- epilogue ----
  #pragma unroll
  for (int m = 0; m < 2; ++m)
    #pragma unroll
    for (int nd = 0; nd < 4; ++nd)
      #pragma unroll
      for (int rr = 0; rr < 4; ++rr) {
        const int row = w * WWIN + wave * 32 + m * 16 + fq * 4 + rr;
        const int col = hd * DH + nd * 16 + fr;
        __hip_bfloat16 b = __float2bfloat16(oacc[m][nd][rr] * inv_[m][rr]);
        CTX[(size_t)row * DIMM + col] = *(u16*)&b;
      }
}

// ---------------- launch ----------------
extern "C" void kernel_launch(void* const* d_in, const int* in_sizes, int n_in,
                              void* d_out, int out_size, void* d_ws, size_t ws_size,
                              hipStream_t stream) {
  const int*   x         = (const int*)d_in[0];
  const float* token_emb = (const float*)d_in[1];
  const float* pos_emb   = (const float*)d_in[2];
  // d_in[3..14]: global-transformer params — dead (fully masked), unused.
  const float* ln1_g = (const float*)d_in[15];
  const float* ln1_b = (const float*)d_in[16];
  const float* wq    = (const float*)d_in[17];
  const float* wkv   = (const float*)d_in[18];
  const float* wo    = (const float*)d_in[19];
  const float* bo    = (const float*)d_in[20];
  const float* ln2_g = (const float*)d_in[21];
  const float* ln2_b = (const float*)d_in[22];
  const float* w1    = (const float*)d_in[23];
  const float* b1    = (const float*)d_in[24];
  const float* w2    = (const float*)d_in[25];
  const float* b2    = (const float*)d_in[26];
  const float* f_ln_g = (const float*)d_in[27];
  const float* f_ln_b = (const float*)d_in[28];
  const float* w_logits = (const float*)d_in[29];
  const float* b_logits = (const float*)d_in[30];
  float* out = (float*)d_out;

  // --- scratch in d_out (fully rewritten by final logits GEMM) ---
  char* ob = (char*)d_out;
  float* h    = (float*)(ob + 0);          // 12.58 MB f32 residual stream
  u16* qk     = (u16*)(ob + 12582912);     // 12.58 MB bf16 [4096][1536]
  u16* ctx    = (u16*)(ob + 25165824);     // 6.29 MB bf16
  u16* mid    = (u16*)(ob + 31457280);     // 25.17 MB bf16 FFN mid
  u16* warena = (u16*)(ob + 56623104);     // 51.9 MB bf16 transposed weights
  const size_t WQ_SZ = (size_t)DIMM * DIMM;     // 589824
  const size_t W1_SZ = (size_t)DIMM * FFDIM;    // 2359296
  const size_t LW = 3 * WQ_SZ + 2 * W1_SZ;
  u16* qkw_t = warena;                 // [1536][768]: rows 0..767 = wq^T, 768.. = wk^T
  u16* wo_t  = warena + 2 * WQ_SZ;
  u16* w1_t  = warena + 3 * WQ_SZ;
  u16* w2_t  = warena + 3 * WQ_SZ + W1_SZ;

  // --- scratch in d_ws (live during final logits GEMM) ---
  u16* wlog_t = (u16*)d_ws;                                           // 49.15 MB
  __hip_bfloat16* lnbuf = (__hip_bfloat16*)((char*)d_ws + 49152000);  // 6.29 MB

  // ---- weight prep ----
  wprep_kernel<<<dim3(24, 24, 4), 256, 0, stream>>>(wq,  qkw_t,         DIMM,   DIMM,  WQ_SZ,   LW);
  wprep_kernel<<<dim3(24, 24, 4), 256, 0, stream>>>(wkv, qkw_t + WQ_SZ, 2*DIMM, DIMM,  2*WQ_SZ, LW);
  wprep_kernel<<<dim3(24, 24, 4), 256, 0, stream>>>(wo,  wo_t,          DIMM,   DIMM,  WQ_SZ,   LW);
  wprep_kernel<<<dim3(96, 24, 4), 256, 0, stream>>>(w1,  w1_t,          FFDIM,  DIMM,  W1_SZ,   LW);
  wprep_kernel<<<dim3(24, 96, 4), 256, 0, stream>>>(w2,  w2_t,          DIMM,   FFDIM, W1_SZ,   LW);
  wprep_kernel<<<dim3(1000, 24, 1), 256, 0, stream>>>(w_logits, wlog_t, NTOK, DIMM, 0, 0);

  embed_kernel<<<SEQLEN, 256, 0, stream>>>(x, token_emb, pos_emb, h);

  for (int l = 0; l < NDEPTH; ++l) {
    ln_kernel<<<SEQLEN, 256, 0, stream>>>(h, ln1_g + l * DIMM, ln1_b + l * DIMM, lnbuf);
    gemm_bf16<64, 128><<<dim3(12, 64), 256, 0, stream>>>(
        (const u16*)lnbuf, qkw_t + l * LW, nullptr, nullptr, qk, DIMM, QKLD, 0, 1);
    attn_mfma<<<dim3(NBUCK, NHEADS), 256, 0, stream>>>(qk, ctx);
    gemm_bf16<64, 64><<<dim3(12, 64), 256, 0, stream>>>(
        ctx, wo_t + l * LW, bo + l * DIMM, h, h, DIMM, DIMM, 0, 0);
    ln_kernel<<<SEQLEN, 256, 0, stream>>>(h, ln2_g + l * DIMM, ln2_b + l * DIMM, lnbuf);
    gemm_bf16<64, 128><<<dim3(24, 64), 256, 0, stream>>>(
        (const u16*)lnbuf, w1_t + l * LW, b1 + l * FFDIM, nullptr, mid, DIMM, FFDIM, 1, 1);
    gemm_bf16<64, 64><<<dim3(12, 64), 256, 0, stream>>>(
        mid, w2_t + l * LW, b2 + l * DIMM, h, h, FFDIM, DIMM, 0, 0);
  }

  ln_kernel<<<SEQLEN, 256, 0, stream>>>(h, f_ln_g, f_ln_b, lnbuf);
  gemm256<<<dim3(NTOK / 256, SEQLEN / 256), 512, 0, stream>>>(
      (const u16*)lnbuf, wlog_t, b_logits, out, DIMM, NTOK);
}